// Round 14
// baseline (668.913 us; speedup 1.0000x reference)
//
#include <hip/hip_runtime.h>
#include <hip/hip_bf16.h>

// Llama attention block: B=2, S=2048, H=4096, NH=32, NKV=8, HD=128, GQA 4:1.
// Pipeline (bf16 MFMA, fp32 accumulate):
//   1. convert hidden -> bf16; Wq/Wk/Wv -> bf16 in one dispatch
//   2. QKV = X @ Wqkv^T : 128^2-tile PIPELINED GEMM (read-ahead frags,
//      2 blocks/CU, counted vmcnt(4)/phase)
//   3. RoPE (Q,K) + scatter, bf16x8-vectorized; fold 1/sqrt(128) into Q
//   4. V transpose: QKV -> Vtg [b][hkv][128 d][2048 s]
//   5. flash attention (causal): KVBLK=64, double-buffered LDS (r5 proven)
//   6. out = AttnOut @ Wo^T (fp32), same GEMM

typedef __bf16 bf16;
typedef __bf16 bf16x8 __attribute__((ext_vector_type(8)));
typedef float f32x4 __attribute__((ext_vector_type(4)));

#define UNROLL _Pragma("unroll")

__device__ __forceinline__ void async16(const bf16* g, bf16* l) {
  __builtin_amdgcn_global_load_lds(
      (const __attribute__((address_space(1))) void*)g,
      (__attribute__((address_space(3))) void*)l,
      16, 0, 0);
}

#define BARR { __builtin_amdgcn_s_barrier(); }
#define VMCNT(n) { asm volatile("s_waitcnt vmcnt(" #n ")" ::: "memory"); }

// ---------------- fp32 -> bf16 convert (8 elem/thread) ----------------
__global__ void k_cvt(const float* __restrict__ s, bf16* __restrict__ d, int n8) {
  int i = blockIdx.x * 256 + threadIdx.x;
  if (i >= n8) return;
  const float4* sp = (const float4*)s + (size_t)i * 2;
  float4 a = sp[0], b = sp[1];
  bf16x8 o = { (bf16)a.x, (bf16)a.y, (bf16)a.z, (bf16)a.w,
               (bf16)b.x, (bf16)b.y, (bf16)b.z, (bf16)b.w };
  *(bf16x8*)(d + (size_t)i * 8) = o;
}

// ---------------- Wq/Wk/Wv converts in one dispatch ----------------------
__global__ void k_cvtw3(const float* __restrict__ Wq, const float* __restrict__ Wk,
                        const float* __restrict__ Wv, bf16* __restrict__ Wqkv) {
  int u = blockIdx.x * 256 + threadIdx.x;
  const float* sp;
  bf16* dp;
  size_t off;
  if (u < 2097152) { sp = Wq; dp = Wqkv; off = u; }
  else if (u < 2621440) { sp = Wk; dp = Wqkv + 16777216u; off = u - 2097152; }
  else { sp = Wv; dp = Wqkv + 20971520u; off = u - 2621440; }
  const float4* s4 = (const float4*)sp + off * 2;
  float4 a = s4[0], b = s4[1];
  bf16x8 o = { (bf16)a.x, (bf16)a.y, (bf16)a.z, (bf16)a.w,
               (bf16)b.x, (bf16)b.y, (bf16)b.z, (bf16)b.w };
  *(bf16x8*)(dp + off * 8) = o;
}

// ---------------- 128^2 pipelined GEMM: C[M,N] = A[M,K] * Bw[N,K]^T ------
// 4 waves (2M x 2N), wave out 64x64, acc[4][4] (64 AGPR). BK=64, 2 phases
// per K-tile. LDS: 2 sides x units {A-kh0, A-kh1, B-kh0, B-kh1}, unit
// [128][32] bf16 (8 KiB) = 64 KiB total -> 2 blocks/CU.
// Swizzle: byte p ^= ((p>>7)&3)<<4 (involution; inverse on gload source).
// READ-AHEAD: phase p reads phase p+1's fragments into alternate register
// buffers, so ds_read latency hides under MFMA (the 44%-plateau fix).
//   phase (t,ks0): read A(s,kh1)+B(s,kh1)->buf0; stage side s^1 u1/u3 of
//                  tile t+1; MFMA buf1 (kh0); vmcnt(4)
//   phase (t,ks1): read A(s^1,kh0)+B(s^1,kh0)->buf1; stage side s u0/u2 of
//                  tile t+2; MFMA buf0 (kh1); vmcnt(4)
// Ledger: tile X u0/u2 staged (X-2,ks1), read (X-1,ks1): vmcnt(4) chain
// lands them 1 phase early; u1/u3 staged (X-1,ks0), read (X,ks0): ditto.
// WAR: every unit rewritten >=2 phases after its last (read-ahead) read,
// with a barrier between. Tail: vmcnt(0) at (NT-2,ks1); (NT-1) stages none.
template <typename OutT>
__global__ __launch_bounds__(256, 2) void k_gemmPL(
    const bf16* __restrict__ A, const bf16* __restrict__ Bw,
    OutT* __restrict__ C, int K, int N, int nbx) {
  __shared__ __align__(16) bf16 lds[2][4][4096];  // 64 KiB
  const int tid = threadIdx.x;
  const int lane = tid & 63;
  const int w = tid >> 6;             // 0..3
  const int wm = w >> 1, wn = w & 1;  // 2M x 2N, wave out 64x64
  const int l16 = lane & 15, lh = lane >> 4;

  // XCD bijective swizzle (grid % 8 == 0)
  const int cpx = gridDim.x >> 3;
  const int swz = (blockIdx.x & 7) * cpx + (blockIdx.x >> 3);
  const int by = swz / nbx, bx = swz % nbx;
  const size_t m0 = (size_t)by * 128, n0 = (size_t)bx * 128;

  // staging constants: unit [128][32]; thread covers 2 x 16B chunks
  // (rows 0..63 at tid*16B, rows 64..127 at +4KB). Source inverse-swizzled.
  const int row0 = tid >> 2;                          // 0..63
  const int cOff = ((tid & 3) ^ ((tid >> 3) & 3)) * 8;
  const bf16* pAa = A + (m0 + row0) * K + cOff;
  const bf16* pAb = pAa + (size_t)64 * K;
  const bf16* pBa = Bw + (n0 + row0) * K + cOff;
  const bf16* pBb = pBa + (size_t)64 * K;

#define SAU(s, h, t)                                      \
  { const int kk = (t) * 64 + (h) * 32;                   \
    async16(pAa + kk, &lds[s][h][0] + tid * 8);           \
    async16(pAb + kk, &lds[s][h][0] + 2048 + tid * 8); }
#define SBU(s, h, t)                                      \
  { const int kk = (t) * 64 + (h) * 32;                   \
    async16(pBa + kk, &lds[s][2 + (h)][0] + tid * 8);     \
    async16(pBb + kk, &lds[s][2 + (h)][0] + 2048 + tid * 8); }

#define RD_A(dst, s, h)                                               \
  UNROLL for (int x = 0; x < 4; ++x) {                                \
    int p = (wm * 64 + x * 16 + l16) * 64 + lh * 16;                  \
    p ^= ((p >> 7) & 3) << 4;                                         \
    dst[x] = *(const bf16x8*)((const char*)&lds[s][h][0] + p);        \
  }
#define RD_B(dst, s, h)                                               \
  UNROLL for (int y = 0; y < 4; ++y) {                                \
    int p = (wn * 64 + y * 16 + l16) * 64 + lh * 16;                  \
    p ^= ((p >> 7) & 3) << 4;                                         \
    dst[y] = *(const bf16x8*)((const char*)&lds[s][2 + (h)][0] + p);  \
  }
#define MFM(Asrc, Bsrc)                                               \
  { __builtin_amdgcn_s_setprio(1);                                    \
    UNROLL for (int x = 0; x < 4; ++x)                                \
      UNROLL for (int y = 0; y < 4; ++y)                              \
        acc[x][y] = __builtin_amdgcn_mfma_f32_16x16x32_bf16(          \
            Asrc[x], Bsrc[y], acc[x][y], 0, 0, 0);                    \
    __builtin_amdgcn_s_setprio(0); }

  f32x4 acc[4][4] = {};
  const int NT = K >> 6;  // K-tiles of 64
  bf16x8 Ar0[4], Br0[4], Ar1[4], Br1[4];

  // prologue: t0 full (u0..u3), t1 u0/u2 = 12 loads; drain t0's 8
  SAU(0, 0, 0); SBU(0, 0, 0); SAU(0, 1, 0); SBU(0, 1, 0);
  SAU(1, 0, 1); SBU(1, 0, 1);
  VMCNT(4);
  BARR;
  // pre-loop read: frags for (0,ks0) = A(s0,kh0), B(s0,kh0)
  RD_A(Ar1, 0, 0); RD_B(Br1, 0, 0);

  for (int t = 0; t < NT; ++t) {
    const int s = t & 1;
    // ---- phase ks0: compute kh0 of tile t ----
    BARR;
    RD_A(Ar0, s, 1); RD_B(Br0, s, 1);  // frags for ks1
    if (t + 1 < NT) { SAU(s ^ 1, 1, t + 1); SBU(s ^ 1, 1, t + 1); }
    MFM(Ar1, Br1);
    if (t + 1 < NT) VMCNT(4);
    // ---- phase ks1: compute kh1 of tile t ----
    BARR;
    if (t + 1 < NT) { RD_A(Ar1, s ^ 1, 0); RD_B(Br1, s ^ 1, 0); }  // frags for next ks0
    if (t + 2 < NT) { SAU(s, 0, t + 2); SBU(s, 0, t + 2); }
    MFM(Ar0, Br0);
    if (t + 2 < NT) { VMCNT(4); } else if (t + 2 == NT) { VMCNT(0); }
  }

  // C write: row = m0 + wm*64 + mi*16 + lh*4 + j ; col = n0 + wn*64 + ni*16 + l16
  UNROLL for (int mi = 0; mi < 4; ++mi) {
    size_t row = m0 + wm * 64 + mi * 16 + lh * 4;
    UNROLL for (int ni = 0; ni < 4; ++ni) {
      size_t col = n0 + wn * 64 + ni * 16 + l16;
      UNROLL for (int j = 0; j < 4; ++j)
        C[(row + j) * N + col] = (OutT)acc[mi][ni][j];
    }
  }
#undef SAU
#undef SBU
#undef RD_A
#undef RD_B
#undef MFM
}

// ---------------- RoPE + scatter (Q,K), bf16x8-vectorized ----------------
__global__ void k_rope(const bf16* __restrict__ QKV, bf16* __restrict__ Qr,
                       bf16* __restrict__ Kr) {
  int gid = blockIdx.x * 256 + threadIdx.x;  // < 1310720
  int seg = gid & 7;
  int rest = gid >> 3;
  int slot = rest % 40;
  int tok = rest / 40;
  int s = tok & 2047;
  int b = tok >> 11;
  const bf16* src = QKV + (size_t)tok * 6144 + slot * 128 + seg * 8;
  bf16x8 a = *(const bf16x8*)src;
  bf16x8 c = *(const bf16x8*)(src + 64);
  bf16x8 o1v, o2v;
  const float scale = (slot < 32) ? 0.08838834764831845f : 1.0f;
  UNROLL for (int j = 0; j < 8; ++j) {
    int p = seg * 8 + j;
    float f = exp2f((float)p * (-13.287712379549449f / 64.0f));
    float sn, cn;
    sincosf((float)s * f, &sn, &cn);
    float x1 = (float)a[j], x2 = (float)c[j];
    o1v[j] = (bf16)((x1 * cn - x2 * sn) * scale);
    o2v[j] = (bf16)((x2 * cn + x1 * sn) * scale);
  }
  bf16* dst;
  if (slot < 32) {
    dst = Qr + (((size_t)b * 32 + slot) * 2048 + s) * 128 + seg * 8;
  } else {
    dst = Kr + (((size_t)b * 8 + (slot - 32)) * 2048 + s) * 128 + seg * 8;
  }
  *(bf16x8*)dst = o1v;
  *(bf16x8*)(dst + 64) = o2v;
}

// ---------------- V transpose: QKV[tok][5120+hkv*128+d] -> Vtg[b][hkv][d][s]
__global__ void k_vtrans(const bf16* __restrict__ QKV, bf16* __restrict__ Vtg) {
  __shared__ __align__(16) bf16 T[64 * 64];
  const int tid = threadIdx.x;
  const int dt = blockIdx.x & 1;
  const int st = (blockIdx.x >> 1) & 31;
  const int hh = blockIdx.x >> 6;
  const int hkv = hh & 7, b = hh >> 3;
  const int s0 = st * 64, d0 = dt * 64;
  const bf16* src = QKV + (size_t)(b * 2048 + s0) * 6144 + 5120 + hkv * 128 + d0;
  UNROLL for (int k = 0; k < 2; ++k) {
    int cc = tid * 2 + k;
    int r = cc >> 3, c8 = cc & 7;
    bf16x8 v = *(const bf16x8*)(src + (size_t)r * 6144 + c8 * 8);
    int byte = (r * 128 + c8 * 16) ^ ((r & 7) << 4);
    *(bf16x8*)((char*)T + byte) = v;
  }
  __syncthreads();
  bf16* dst = Vtg + ((size_t)(b * 8 + hkv) * 128 + d0) * 2048 + s0;
  UNROLL for (int k = 0; k < 2; ++k) {
    int cc = tid * 2 + k;
    int d = cc >> 3, s8 = cc & 7;
    bf16x8 v;
    UNROLL for (int j = 0; j < 8; ++j) {
      int s = s8 * 8 + j;
      int byte = (s * 128 + d * 2) ^ ((s & 7) << 4);
      v[j] = *(const bf16*)((const char*)T + byte);
    }
    *(bf16x8*)(dst + (size_t)d * 2048 + s8 * 8) = v;
  }
}

// ---------------- flash attention (causal, GQA 4:1) — r5 proven version --
__global__ __launch_bounds__(256, 2) void k_flash(
    const bf16* __restrict__ Qr, const bf16* __restrict__ Kr,
    const bf16* __restrict__ Vtg, bf16* __restrict__ Out) {
  __shared__ __align__(16) bf16 Kl[2][64 * 128];
  __shared__ __align__(16) bf16 Vl[2][128 * 64];
  __shared__ __align__(16) bf16 Pl[4][32 * 64];
  const int tid = threadIdx.x;
  const int lane = tid & 63;
  const int w = tid >> 6;
  const int l16 = lane & 15, lh = lane >> 4;
  const int pid = blockIdx.x & 7;
  const int hl = blockIdx.x >> 3;
  const int h = hl & 31, b = hl >> 5;
  const int hkv = h >> 2;
  const bf16* Kbase = Kr + ((size_t)(b * 8 + hkv)) * 2048 * 128;
  const bf16* Vbase = Vtg + ((size_t)(b * 8 + hkv)) * 128 * 2048;
  bf16* P = &Pl[w][0];

  int kOff[4], vOff[4], ldsOff[4];
  UNROLL for (int i = 0; i < 4; ++i) {
    int c = (w * 4 + i) * 64 + lane;
    ldsOff[i] = c * 8;
    int r = c >> 4, p = c & 15;
    kOff[i] = r * 128 + (p ^ (r & 7)) * 8;
    int r2 = c >> 3, p2 = c & 7;
    vOff[i] = r2 * 2048 + (p2 ^ (r2 & 7)) * 8;
  }

  for (int qi = 0; qi < 2; ++qi) {
    const int q = qi ? (15 - pid) : pid;
    const int q0 = q * 128;
    const int nt = 2 * q + 2;

    bf16x8 qf[2][4];
    UNROLL for (int m = 0; m < 2; ++m) {
      const bf16* qb = Qr + (((size_t)(b * 32 + h)) * 2048 + q0 + w * 32 + m * 16 + l16) * 128 + lh * 8;
      UNROLL for (int kc = 0; kc < 4; ++kc) qf[m][kc] = *(const bf16x8*)(qb + kc * 32);
    }
    f32x4 acc[2][8] = {};
    float mrow[2][4] = {{-1e30f, -1e30f, -1e30f, -1e30f}, {-1e30f, -1e30f, -1e30f, -1e30f}};
    float lrow[2][4] = {};

    UNROLL for (int i = 0; i < 4; ++i) {
      async16(Kbase + kOff[i], &Kl[0][0] + ldsOff[i]);
      async16(Vbase + vOff[i], &Vl[0][0] + ldsOff[i]);
    }
    __syncthreads();

    for (int t = 0; t < nt; ++t) {
      const int cur = t & 1;
      if (t + 1 < nt) {
        const int nb = t + 1;
        UNROLL for (int i = 0; i < 4; ++i) {
          async16(Kbase + (size_t)nb * 8192 + kOff[i], &Kl[cur ^ 1][0] + ldsOff[i]);
          async16(Vbase + (size_t)nb * 64 + vOff[i], &Vl[cur ^ 1][0] + ldsOff[i]);
        }
      }
      f32x4 sf[2][4] = {};
      UNROLL for (int ni = 0; ni < 4; ++ni) {
        int row = ni * 16 + l16;
        bf16x8 kf[4];
        UNROLL for (int kc = 0; kc < 4; ++kc) {
          int byte = (row * 256 + kc * 64 + lh * 16) ^ ((row & 7) << 4);
          kf[kc] = *(const bf16x8*)((const char*)&Kl[cur][0] + byte);
        }
        UNROLL for (int m = 0; m < 2; ++m)
          UNROLL for (int kc = 0; kc < 4; ++kc)
            sf[m][ni] = __builtin_amdgcn_mfma_f32_16x16x32_bf16(qf[m][kc], kf[kc], sf[m][ni], 0, 0, 0);
      }
      if (t >= 2 * q) {
        UNROLL for (int m = 0; m < 2; ++m)
          UNROLL for (int ni = 0; ni < 4; ++ni) {
            int key = t * 64 + ni * 16 + l16;
            UNROLL for (int j = 0; j < 4; ++j) {
              int rowg = q0 + w * 32 + m * 16 + lh * 4 + j;
              if (key > rowg) sf[m][ni][j] = -1e30f;
            }
          }
      }
      float corr[2][4];
      UNROLL for (int m = 0; m < 2; ++m)
        UNROLL for (int j = 0; j < 4; ++j) {
          float mx = fmaxf(fmaxf(sf[m][0][j], sf[m][1][j]), fmaxf(sf[m][2][j], sf[m][3][j]));
          mx = fmaxf(mx, __shfl_xor(mx, 1));
          mx = fmaxf(mx, __shfl_xor(mx, 2));
          mx = fmaxf(mx, __shfl_xor(mx, 4));
          mx = fmaxf(mx, __shfl_xor(mx, 8));
          float mn = fmaxf(mrow[m][j], mx);
          corr[m][j] = __expf(mrow[m][j] - mn);
          mrow[m][j] = mn;
          float rs = 0.f;
          UNROLL for (int ni = 0; ni < 4; ++ni) {
            float pv = __expf(sf[m][ni][j] - mn);
            sf[m][ni][j] = pv;
            rs += pv;
          }
          rs += __shfl_xor(rs, 1);
          rs += __shfl_xor(rs, 2);
          rs += __shfl_xor(rs, 4);
          rs += __shfl_xor(rs, 8);
          lrow[m][j] = lrow[m][j] * corr[m][j] + rs;
        }
      UNROLL for (int m = 0; m < 2; ++m)
        UNROLL for (int di = 0; di < 8; ++di)
          UNROLL for (int j = 0; j < 4; ++j) acc[m][di][j] *= corr[m][j];
      UNROLL for (int m = 0; m < 2; ++m)
        UNROLL for (int ni = 0; ni < 4; ++ni)
          UNROLL for (int j = 0; j < 4; ++j) {
            int row = m * 16 + lh * 4 + j;
            int byte = (row * 128 + ni * 32 + l16 * 2) ^ ((row & 7) << 4);
            *(bf16*)((char*)P + byte) = (bf16)sf[m][ni][j];
          }
      UNROLL for (int kc = 0; kc < 2; ++kc) {
        bf16x8 pa[2];
        UNROLL for (int m = 0; m < 2; ++m) {
          int row = m * 16 + l16;
          int byte = (row * 128 + kc * 64 + lh * 16) ^ ((row & 7) << 4);
          pa[m] = *(const bf16x8*)((const char*)P + byte);
        }
        UNROLL for (int di = 0; di < 8; ++di) {
          int d = di * 16 + l16;
          int byte = (d * 128 + kc * 64 + lh * 16) ^ ((d & 7) << 4);
          bf16x8 vb = *(const bf16x8*)((const char*)&Vl[cur][0] + byte);
          UNROLL for (int m = 0; m < 2; ++m)
            acc[m][di] = __builtin_amdgcn_mfma_f32_16x16x32_bf16(pa[m], vb, acc[m][di], 0, 0, 0);
        }
      }
      __syncthreads();
    }

    UNROLL for (int m = 0; m < 2; ++m)
      UNROLL for (int j = 0; j < 4; ++j) {
        float inv = 1.0f / lrow[m][j];
        int rowg = q0 + w * 32 + m * 16 + lh * 4 + j;
        bf16* ob = Out + ((size_t)(b * 2048) + rowg) * 4096 + h * 128 + l16;
        UNROLL for (int di = 0; di < 8; ++di)
          ob[di * 16] = (bf16)(acc[m][di][j] * inv);
      }
  }
}

// ---------------- launch ----------------
extern "C" void kernel_launch(void* const* d_in, const int* in_sizes, int n_in,
                              void* d_out, int out_size, void* d_ws, size_t ws_size,
                              hipStream_t stream) {
  const float* hidden = (const float*)d_in[0];
  const float* Wq = (const float*)d_in[3];
  const float* Wk = (const float*)d_in[4];
  const float* Wv = (const float*)d_in[5];
  const float* Wo = (const float*)d_in[6];
  float* out = (float*)d_out;

  // workspace layout (bytes):
  //   Xb   [4096*4096] bf16 @ 0        (reused as AttnOut)
  //   Wqkv [6144*4096] bf16 @ 32M      (reused as Wo_bf16 after gemm1)
  //   QKV  [4096*6144] bf16 @ 80M
  //   Qr   [2,32,2048,128] bf16 @ 128M
  //   Kr   [2,8,2048,128]  bf16 @ 160M
  //   Vtg  [2,8,128,2048]  bf16 @ 168M   total 176 MiB
  char* ws = (char*)d_ws;
  if (ws_size < 184549376u) return;
  bf16* Xb = (bf16*)(ws);
  bf16* Wqkv = (bf16*)(ws + 33554432u);
  bf16* QKV = (bf16*)(ws + 83886080u);
  bf16* Qr = (bf16*)(ws + 134217728u);
  bf16* Kr = (bf16*)(ws + 167772160u);
  bf16* Vtg = (bf16*)(ws + 176160768u);
  bf16* AttnO = Xb;
  bf16* Wob = Wqkv;

  k_cvt<<<8192, 256, 0, stream>>>(hidden, Xb, 2097152);
  k_cvtw3<<<12288, 256, 0, stream>>>(Wq, Wk, Wv, Wqkv);
  // QKV GEMM: 32 x 48 = 1536 blocks (128^2 tiles, 2 blocks/CU, 3 full waves)
  k_gemmPL<bf16><<<1536, 256, 0, stream>>>(Xb, Wqkv, QKV, 4096, 6144, 48);
  k_rope<<<5120, 256, 0, stream>>>(QKV, Qr, Kr);
  k_vtrans<<<1024, 256, 0, stream>>>(QKV, Vtg);
  k_cvt<<<8192, 256, 0, stream>>>(Wo, Wob, 2097152);
  k_flash<<<512, 256, 0, stream>>>(Qr, Kr, Vtg, AttnO);
  // O-proj: 32 x 32 = 1024 blocks (2 full waves)
  k_gemmPL<float><<<1024, 256, 0, stream>>>(AttnO, Wob, out, 4096, 4096, 32);
}

// Round 15
// 576.400 us; speedup vs baseline: 1.1605x; 1.1605x over previous
//
#include <hip/hip_runtime.h>
#include <hip/hip_bf16.h>

// Llama attention block: B=2, S=2048, H=4096, NH=32, NKV=8, HD=128, GQA 4:1.
// Pipeline (bf16 MFMA, fp32 accumulate):
//   1. convert hidden -> bf16; Wq/Wk/Wv -> bf16 in one dispatch
//   2. QKV = X @ Wqkv^T  (256^2 8-phase GEMM, compiler-scheduled — r10 best)
//   3. RoPE (Q,K) + scatter, bf16x8-vectorized; fold 1/sqrt(128) into Q
//   4. V transpose: QKV -> Vtg [b][hkv][128 d][2048 s]
//   5. flash attention (causal): KVBLK=64, dbuf LDS, COUNTED-vmcnt raw
//      barriers (prefetch survives the barrier — fixes the per-tile drain)
//   6. out = AttnOut @ Wo^T (fp32), same GEMM

typedef __bf16 bf16;
typedef __bf16 bf16x8 __attribute__((ext_vector_type(8)));
typedef float f32x4 __attribute__((ext_vector_type(4)));

#define UNROLL _Pragma("unroll")

__device__ __forceinline__ void async16(const bf16* g, bf16* l) {
  __builtin_amdgcn_global_load_lds(
      (const __attribute__((address_space(1))) void*)g,
      (__attribute__((address_space(3))) void*)l,
      16, 0, 0);
}

#define BARR { __builtin_amdgcn_s_barrier(); }
#define VMCNT(n) { asm volatile("s_waitcnt vmcnt(" #n ")" ::: "memory"); }

// ---------------- fp32 -> bf16 convert (8 elem/thread) ----------------
__global__ void k_cvt(const float* __restrict__ s, bf16* __restrict__ d, int n8) {
  int i = blockIdx.x * 256 + threadIdx.x;
  if (i >= n8) return;
  const float4* sp = (const float4*)s + (size_t)i * 2;
  float4 a = sp[0], b = sp[1];
  bf16x8 o = { (bf16)a.x, (bf16)a.y, (bf16)a.z, (bf16)a.w,
               (bf16)b.x, (bf16)b.y, (bf16)b.z, (bf16)b.w };
  *(bf16x8*)(d + (size_t)i * 8) = o;
}

// ---------------- Wq/Wk/Wv converts in one dispatch ----------------------
__global__ void k_cvtw3(const float* __restrict__ Wq, const float* __restrict__ Wk,
                        const float* __restrict__ Wv, bf16* __restrict__ Wqkv) {
  int u = blockIdx.x * 256 + threadIdx.x;
  const float* sp;
  bf16* dp;
  size_t off;
  if (u < 2097152) { sp = Wq; dp = Wqkv; off = u; }
  else if (u < 2621440) { sp = Wk; dp = Wqkv + 16777216u; off = u - 2097152; }
  else { sp = Wv; dp = Wqkv + 20971520u; off = u - 2621440; }
  const float4* s4 = (const float4*)sp + off * 2;
  float4 a = s4[0], b = s4[1];
  bf16x8 o = { (bf16)a.x, (bf16)a.y, (bf16)a.z, (bf16)a.w,
               (bf16)b.x, (bf16)b.y, (bf16)b.z, (bf16)b.w };
  *(bf16x8*)(dp + off * 8) = o;
}

// ---------------- 256^2 single-barrier 8-phase GEMM (r10 best) -----------
template <typename OutT>
__global__ __launch_bounds__(512, 2) void k_gemmCS(
    const bf16* __restrict__ A, const bf16* __restrict__ Bw,
    OutT* __restrict__ C, int K, int N, int nbx) {
  __shared__ __align__(16) bf16 lds[2][4][8192];  // 128 KiB
  const int tid = threadIdx.x;
  const int lane = tid & 63;
  const int w = tid >> 6;
  const int wm = w >> 2, wn = w & 3;  // 2M x 4N, wave out 128x64
  const int l16 = lane & 15, lh = lane >> 4;

  const int cpx = gridDim.x >> 3;
  const int swz = (blockIdx.x & 7) * cpx + (blockIdx.x >> 3);
  const int by = swz / nbx, bx = swz % nbx;
  const size_t m0 = (size_t)by * 256, n0 = (size_t)bx * 256;

  const int row0 = tid >> 2;
  const int cOff = ((tid & 3) ^ ((row0 >> 1) & 3)) * 8;
  const bf16* pA0 = A + (m0 + row0) * K + cOff;
  const bf16* pA1 = pA0 + (size_t)128 * K;
  const bf16* pB0 = Bw + (n0 + row0) * K + cOff;
  const bf16* pB1 = pB0 + (size_t)128 * K;

#define SA(s, h, t)                                        \
  { const int kk = (t) * 64 + (h) * 32;                    \
    async16(pA0 + kk, &lds[s][h][0] + tid * 8);            \
    async16(pA1 + kk, &lds[s][h][0] + 4096 + tid * 8); }
#define SB(s, h, t)                                        \
  { const int kk = (t) * 64 + (h) * 32;                    \
    async16(pB0 + kk, &lds[s][2 + (h)][0] + tid * 8);      \
    async16(pB1 + kk, &lds[s][2 + (h)][0] + 4096 + tid * 8); }

#define RDA(s, u, mh)                                                 \
  UNROLL for (int x = 0; x < 4; ++x) {                                \
    int p = (wm * 128 + (mh) * 64 + x * 16 + l16) * 64 + lh * 16;     \
    p ^= ((p >> 7) & 3) << 4;                                         \
    Ar[x] = *(const bf16x8*)((const char*)&lds[s][u][0] + p);         \
  }
#define RDB(s, u)                                                     \
  UNROLL for (int y = 0; y < 4; ++y) {                                \
    int p = (wn * 64 + y * 16 + l16) * 64 + lh * 16;                  \
    p ^= ((p >> 7) & 3) << 4;                                         \
    Br[y] = *(const bf16x8*)((const char*)&lds[s][u][0] + p);         \
  }
#define MF(mh)                                                        \
  { __builtin_amdgcn_s_setprio(1);                                    \
    UNROLL for (int x = 0; x < 4; ++x)                                \
      UNROLL for (int y = 0; y < 4; ++y)                              \
        acc[(mh) * 4 + x][y] = __builtin_amdgcn_mfma_f32_16x16x32_bf16( \
            Ar[x], Br[y], acc[(mh) * 4 + x][y], 0, 0, 0);             \
    __builtin_amdgcn_s_setprio(0); }

  f32x4 acc[8][4] = {};
  const int NITER = K >> 7;

  SA(0, 0, 0); SB(0, 0, 0); SA(0, 1, 0); SB(0, 1, 0); SA(1, 0, 1); SB(1, 0, 1);
  VMCNT(8);

#define ITER_BODY(i, LAST)                                                  \
  { const int t0 = 2 * (i), t1 = t0 + 1;                                    \
    bf16x8 Ar[4], Br[4];                                                    \
    BARR; RDA(0, 0, 0); RDB(0, 2); SA(1, 1, t1); MF(0);                     \
    BARR; RDA(0, 0, 1); SB(1, 1, t1); MF(1); VMCNT(8);                      \
    BARR; RDA(0, 1, 0); RDB(0, 3); if (!(LAST)) SA(0, 0, t0 + 2); MF(0);    \
    BARR; RDA(0, 1, 1); if (!(LAST)) SB(0, 0, t0 + 2); MF(1);               \
    if (LAST) { VMCNT(4); } else { VMCNT(8); }                              \
    BARR; RDA(1, 0, 0); RDB(1, 2); if (!(LAST)) SA(0, 1, t0 + 2); MF(0);    \
    BARR; RDA(1, 0, 1); if (!(LAST)) SB(0, 1, t0 + 2); MF(1);               \
    if (LAST) { VMCNT(0); } else { VMCNT(8); }                              \
    BARR; RDA(1, 1, 0); RDB(1, 3); if (!(LAST)) SA(1, 0, t1 + 2); MF(0);    \
    BARR; RDA(1, 1, 1); if (!(LAST)) SB(1, 0, t1 + 2); MF(1);               \
    if (!(LAST)) VMCNT(8); }

  for (int i = 0; i < NITER - 1; ++i) ITER_BODY(i, 0);
  ITER_BODY(NITER - 1, 1);

  UNROLL for (int mi = 0; mi < 8; ++mi) {
    size_t row = m0 + wm * 128 + mi * 16 + lh * 4;
    UNROLL for (int ni = 0; ni < 4; ++ni) {
      size_t col = n0 + wn * 64 + ni * 16 + l16;
      UNROLL for (int j = 0; j < 4; ++j)
        C[(row + j) * N + col] = (OutT)acc[mi][ni][j];
    }
  }
#undef SA
#undef SB
#undef RDA
#undef RDB
#undef MF
#undef ITER_BODY
}

// ---------------- RoPE + scatter (Q,K), bf16x8-vectorized ----------------
__global__ void k_rope(const bf16* __restrict__ QKV, bf16* __restrict__ Qr,
                       bf16* __restrict__ Kr) {
  int gid = blockIdx.x * 256 + threadIdx.x;  // < 1310720
  int seg = gid & 7;
  int rest = gid >> 3;
  int slot = rest % 40;
  int tok = rest / 40;
  int s = tok & 2047;
  int b = tok >> 11;
  const bf16* src = QKV + (size_t)tok * 6144 + slot * 128 + seg * 8;
  bf16x8 a = *(const bf16x8*)src;
  bf16x8 c = *(const bf16x8*)(src + 64);
  bf16x8 o1v, o2v;
  const float scale = (slot < 32) ? 0.08838834764831845f : 1.0f;
  UNROLL for (int j = 0; j < 8; ++j) {
    int p = seg * 8 + j;
    float f = exp2f((float)p * (-13.287712379549449f / 64.0f));
    float sn, cn;
    sincosf((float)s * f, &sn, &cn);
    float x1 = (float)a[j], x2 = (float)c[j];
    o1v[j] = (bf16)((x1 * cn - x2 * sn) * scale);
    o2v[j] = (bf16)((x2 * cn + x1 * sn) * scale);
  }
  bf16* dst;
  if (slot < 32) {
    dst = Qr + (((size_t)b * 32 + slot) * 2048 + s) * 128 + seg * 8;
  } else {
    dst = Kr + (((size_t)b * 8 + (slot - 32)) * 2048 + s) * 128 + seg * 8;
  }
  *(bf16x8*)dst = o1v;
  *(bf16x8*)(dst + 64) = o2v;
}

// ---------------- V transpose: QKV[tok][5120+hkv*128+d] -> Vtg[b][hkv][d][s]
__global__ void k_vtrans(const bf16* __restrict__ QKV, bf16* __restrict__ Vtg) {
  __shared__ __align__(16) bf16 T[64 * 64];
  const int tid = threadIdx.x;
  const int dt = blockIdx.x & 1;
  const int st = (blockIdx.x >> 1) & 31;
  const int hh = blockIdx.x >> 6;
  const int hkv = hh & 7, b = hh >> 3;
  const int s0 = st * 64, d0 = dt * 64;
  const bf16* src = QKV + (size_t)(b * 2048 + s0) * 6144 + 5120 + hkv * 128 + d0;
  UNROLL for (int k = 0; k < 2; ++k) {
    int cc = tid * 2 + k;
    int r = cc >> 3, c8 = cc & 7;
    bf16x8 v = *(const bf16x8*)(src + (size_t)r * 6144 + c8 * 8);
    int byte = (r * 128 + c8 * 16) ^ ((r & 7) << 4);
    *(bf16x8*)((char*)T + byte) = v;
  }
  __syncthreads();
  bf16* dst = Vtg + ((size_t)(b * 8 + hkv) * 128 + d0) * 2048 + s0;
  UNROLL for (int k = 0; k < 2; ++k) {
    int cc = tid * 2 + k;
    int d = cc >> 3, s8 = cc & 7;
    bf16x8 v;
    UNROLL for (int j = 0; j < 8; ++j) {
      int s = s8 * 8 + j;
      int byte = (s * 128 + d * 2) ^ ((s & 7) << 4);
      v[j] = *(const bf16*)((const char*)T + byte);
    }
    *(bf16x8*)(dst + (size_t)d * 2048 + s8 * 8) = v;
  }
}

// ---------------- flash attention (causal, GQA 4:1) ----------------------
// r5 body with counted-vmcnt raw barriers: per tile, stage t+1 then
// vmcnt(8) (keeps t+1's 8 loads in flight across the barrier; drains
// exactly tile t's). Softmax/swizzles identical to r5 (no spill).
__global__ __launch_bounds__(256, 2) void k_flash(
    const bf16* __restrict__ Qr, const bf16* __restrict__ Kr,
    const bf16* __restrict__ Vtg, bf16* __restrict__ Out) {
  __shared__ __align__(16) bf16 Kl[2][64 * 128];
  __shared__ __align__(16) bf16 Vl[2][128 * 64];
  __shared__ __align__(16) bf16 Pl[4][32 * 64];
  const int tid = threadIdx.x;
  const int lane = tid & 63;
  const int w = tid >> 6;
  const int l16 = lane & 15, lh = lane >> 4;
  const int pid = blockIdx.x & 7;
  const int hl = blockIdx.x >> 3;
  const int h = hl & 31, b = hl >> 5;
  const int hkv = h >> 2;
  const bf16* Kbase = Kr + ((size_t)(b * 8 + hkv)) * 2048 * 128;
  const bf16* Vbase = Vtg + ((size_t)(b * 8 + hkv)) * 128 * 2048;
  bf16* P = &Pl[w][0];

  int kOff[4], vOff[4], ldsOff[4];
  UNROLL for (int i = 0; i < 4; ++i) {
    int c = (w * 4 + i) * 64 + lane;
    ldsOff[i] = c * 8;
    int r = c >> 4, p = c & 15;
    kOff[i] = r * 128 + (p ^ (r & 7)) * 8;
    int r2 = c >> 3, p2 = c & 7;
    vOff[i] = r2 * 2048 + (p2 ^ (r2 & 7)) * 8;
  }

#define STAGE(buf, nb)                                                       \
  UNROLL for (int i = 0; i < 4; ++i) {                                       \
    async16(Kbase + (size_t)(nb) * 8192 + kOff[i], &Kl[buf][0] + ldsOff[i]); \
    async16(Vbase + (size_t)(nb) * 64 + vOff[i], &Vl[buf][0] + ldsOff[i]);   \
  }

  for (int qi = 0; qi < 2; ++qi) {
    const int q = qi ? (15 - pid) : pid;
    const int q0 = q * 128;
    const int nt = 2 * q + 2;

    bf16x8 qf[2][4];
    UNROLL for (int m = 0; m < 2; ++m) {
      const bf16* qb = Qr + (((size_t)(b * 32 + h)) * 2048 + q0 + w * 32 + m * 16 + l16) * 128 + lh * 8;
      UNROLL for (int kc = 0; kc < 4; ++kc) qf[m][kc] = *(const bf16x8*)(qb + kc * 32);
    }
    f32x4 acc[2][8] = {};
    float mrow[2][4] = {{-1e30f, -1e30f, -1e30f, -1e30f}, {-1e30f, -1e30f, -1e30f, -1e30f}};
    float lrow[2][4] = {};

    // prologue: tile 0 into buf 0; own loads drained (cross-wave visibility
    // established by the loop's first barrier)
    STAGE(0, 0);
    VMCNT(0);

    for (int t = 0; t < nt; ++t) {
      const int cur = t & 1;
      if (t + 1 < nt) {
        STAGE(cur ^ 1, t + 1);
        VMCNT(8);   // drain tile t's 8 loads; keep t+1's 8 in flight
      } else {
        VMCNT(0);
      }
      BARR;  // all waves' tile-t chunks visible

      f32x4 sf[2][4] = {};
      UNROLL for (int ni = 0; ni < 4; ++ni) {
        int row = ni * 16 + l16;
        bf16x8 kf[4];
        UNROLL for (int kc = 0; kc < 4; ++kc) {
          int byte = (row * 256 + kc * 64 + lh * 16) ^ ((row & 7) << 4);
          kf[kc] = *(const bf16x8*)((const char*)&Kl[cur][0] + byte);
        }
        UNROLL for (int m = 0; m < 2; ++m)
          UNROLL for (int kc = 0; kc < 4; ++kc)
            sf[m][ni] = __builtin_amdgcn_mfma_f32_16x16x32_bf16(qf[m][kc], kf[kc], sf[m][ni], 0, 0, 0);
      }
      if (t >= 2 * q) {
        UNROLL for (int m = 0; m < 2; ++m)
          UNROLL for (int ni = 0; ni < 4; ++ni) {
            int key = t * 64 + ni * 16 + l16;
            UNROLL for (int j = 0; j < 4; ++j) {
              int rowg = q0 + w * 32 + m * 16 + lh * 4 + j;
              if (key > rowg) sf[m][ni][j] = -1e30f;
            }
          }
      }
      float corr[2][4];
      UNROLL for (int m = 0; m < 2; ++m)
        UNROLL for (int j = 0; j < 4; ++j) {
          float mx = fmaxf(fmaxf(sf[m][0][j], sf[m][1][j]), fmaxf(sf[m][2][j], sf[m][3][j]));
          mx = fmaxf(mx, __shfl_xor(mx, 1));
          mx = fmaxf(mx, __shfl_xor(mx, 2));
          mx = fmaxf(mx, __shfl_xor(mx, 4));
          mx = fmaxf(mx, __shfl_xor(mx, 8));
          float mn = fmaxf(mrow[m][j], mx);
          corr[m][j] = __expf(mrow[m][j] - mn);
          mrow[m][j] = mn;
          float rs = 0.f;
          UNROLL for (int ni = 0; ni < 4; ++ni) {
            float pv = __expf(sf[m][ni][j] - mn);
            sf[m][ni][j] = pv;
            rs += pv;
          }
          rs += __shfl_xor(rs, 1);
          rs += __shfl_xor(rs, 2);
          rs += __shfl_xor(rs, 4);
          rs += __shfl_xor(rs, 8);
          lrow[m][j] = lrow[m][j] * corr[m][j] + rs;
        }
      UNROLL for (int m = 0; m < 2; ++m)
        UNROLL for (int di = 0; di < 8; ++di)
          UNROLL for (int j = 0; j < 4; ++j) acc[m][di][j] *= corr[m][j];
      UNROLL for (int m = 0; m < 2; ++m)
        UNROLL for (int ni = 0; ni < 4; ++ni)
          UNROLL for (int j = 0; j < 4; ++j) {
            int row = m * 16 + lh * 4 + j;
            int byte = (row * 128 + ni * 32 + l16 * 2) ^ ((row & 7) << 4);
            *(bf16*)((char*)P + byte) = (bf16)sf[m][ni][j];
          }
      UNROLL for (int kc = 0; kc < 2; ++kc) {
        bf16x8 pa[2];
        UNROLL for (int m = 0; m < 2; ++m) {
          int row = m * 16 + l16;
          int byte = (row * 128 + kc * 64 + lh * 16) ^ ((row & 7) << 4);
          pa[m] = *(const bf16x8*)((const char*)P + byte);
        }
        UNROLL for (int di = 0; di < 8; ++di) {
          int d = di * 16 + l16;
          int byte = (d * 128 + kc * 64 + lh * 16) ^ ((d & 7) << 4);
          bf16x8 vb = *(const bf16x8*)((const char*)&Vl[cur][0] + byte);
          UNROLL for (int m = 0; m < 2; ++m)
            acc[m][di] = __builtin_amdgcn_mfma_f32_16x16x32_bf16(pa[m], vb, acc[m][di], 0, 0, 0);
        }
      }
      BARR;  // all reads of buf[cur] done before next iter's stage overwrites
    }

    UNROLL for (int m = 0; m < 2; ++m)
      UNROLL for (int j = 0; j < 4; ++j) {
        float inv = 1.0f / lrow[m][j];
        int rowg = q0 + w * 32 + m * 16 + lh * 4 + j;
        bf16* ob = Out + ((size_t)(b * 2048) + rowg) * 4096 + h * 128 + l16;
        UNROLL for (int di = 0; di < 8; ++di)
          ob[di * 16] = (bf16)(acc[m][di][j] * inv);
      }
  }
#undef STAGE
}

// ---------------- launch ----------------
extern "C" void kernel_launch(void* const* d_in, const int* in_sizes, int n_in,
                              void* d_out, int out_size, void* d_ws, size_t ws_size,
                              hipStream_t stream) {
  const float* hidden = (const float*)d_in[0];
  const float* Wq = (const float*)d_in[3];
  const float* Wk = (const float*)d_in[4];
  const float* Wv = (const float*)d_in[5];
  const float* Wo = (const float*)d_in[6];
  float* out = (float*)d_out;

  // workspace layout (bytes):
  //   Xb   [4096*4096] bf16 @ 0        (reused as AttnOut)
  //   Wqkv [6144*4096] bf16 @ 32M      (reused as Wo_bf16 after gemm1)
  //   QKV  [4096*6144] bf16 @ 80M
  //   Qr   [2,32,2048,128] bf16 @ 128M
  //   Kr   [2,8,2048,128]  bf16 @ 160M
  //   Vtg  [2,8,128,2048]  bf16 @ 168M   total 176 MiB
  char* ws = (char*)d_ws;
  if (ws_size < 184549376u) return;
  bf16* Xb = (bf16*)(ws);
  bf16* Wqkv = (bf16*)(ws + 33554432u);
  bf16* QKV = (bf16*)(ws + 83886080u);
  bf16* Qr = (bf16*)(ws + 134217728u);
  bf16* Kr = (bf16*)(ws + 167772160u);
  bf16* Vtg = (bf16*)(ws + 176160768u);
  bf16* AttnO = Xb;
  bf16* Wob = Wqkv;

  k_cvt<<<8192, 256, 0, stream>>>(hidden, Xb, 2097152);
  k_cvtw3<<<12288, 256, 0, stream>>>(Wq, Wk, Wv, Wqkv);
  // QKV GEMM: 16 x 24 = 384 blocks (256^2 tiles, compiler-scheduled phases)
  k_gemmCS<bf16><<<384, 512, 0, stream>>>(Xb, Wqkv, QKV, 4096, 6144, 24);
  k_rope<<<5120, 256, 0, stream>>>(QKV, Qr, Kr);
  k_vtrans<<<1024, 256, 0, stream>>>(QKV, Vtg);
  k_cvt<<<8192, 256, 0, stream>>>(Wo, Wob, 2097152);
  k_flash<<<512, 256, 0, stream>>>(Qr, Kr, Vtg, AttnO);
  // O-proj: 16 x 16 = 256 blocks (one dispatch wave)
  k_gemmCS<float><<<256, 512, 0, stream>>>(AttnO, Wob, out, 4096, 4096, 16);
}

// Round 16
// 556.537 us; speedup vs baseline: 1.2019x; 1.0357x over previous
//
#include <hip/hip_runtime.h>
#include <hip/hip_bf16.h>

// Llama attention block: B=2, S=2048, H=4096, NH=32, NKV=8, HD=128, GQA 4:1.
// Pipeline (bf16 MFMA, fp32 accumulate):
//   1. convert hidden -> bf16; Wq/Wk/Wv -> bf16 in one dispatch
//   2. QKV = X @ Wqkv^T split for exact CU packing:
//      gemm1A: Q-projection cols 0..4095   = 256 tiles, full K  (1 wave)
//      gemm1B: K/V-proj   cols 4096..6143  = 128 tiles x 2 half-K (1 wave),
//              bf16 partials into the (dead) Qr region
//      k_redsum: partial0+partial1 -> QKV cols 4096..6143
//   3. RoPE (Q,K) + scatter, bf16x8-vectorized; fold 1/sqrt(128) into Q
//   4. V transpose: QKV -> Vtg [b][hkv][128 d][2048 s]
//   5. flash attention (causal): KVBLK=64, double-buffered LDS (r5 proven)
//   6. out = AttnOut @ Wo^T (fp32), same 256^2 8-phase GEMM

typedef __bf16 bf16;
typedef __bf16 bf16x8 __attribute__((ext_vector_type(8)));
typedef float f32x4 __attribute__((ext_vector_type(4)));

#define UNROLL _Pragma("unroll")

__device__ __forceinline__ void async16(const bf16* g, bf16* l) {
  __builtin_amdgcn_global_load_lds(
      (const __attribute__((address_space(1))) void*)g,
      (__attribute__((address_space(3))) void*)l,
      16, 0, 0);
}

#define BARR { __builtin_amdgcn_s_barrier(); }
#define VMCNT(n) { asm volatile("s_waitcnt vmcnt(" #n ")" ::: "memory"); }

// ---------------- fp32 -> bf16 convert (8 elem/thread) ----------------
__global__ void k_cvt(const float* __restrict__ s, bf16* __restrict__ d, int n8) {
  int i = blockIdx.x * 256 + threadIdx.x;
  if (i >= n8) return;
  const float4* sp = (const float4*)s + (size_t)i * 2;
  float4 a = sp[0], b = sp[1];
  bf16x8 o = { (bf16)a.x, (bf16)a.y, (bf16)a.z, (bf16)a.w,
               (bf16)b.x, (bf16)b.y, (bf16)b.z, (bf16)b.w };
  *(bf16x8*)(d + (size_t)i * 8) = o;
}

// ---------------- Wq/Wk/Wv converts in one dispatch ----------------------
__global__ void k_cvtw3(const float* __restrict__ Wq, const float* __restrict__ Wk,
                        const float* __restrict__ Wv, bf16* __restrict__ Wqkv) {
  int u = blockIdx.x * 256 + threadIdx.x;
  const float* sp;
  bf16* dp;
  size_t off;
  if (u < 2097152) { sp = Wq; dp = Wqkv; off = u; }
  else if (u < 2621440) { sp = Wk; dp = Wqkv + 16777216u; off = u - 2097152; }
  else { sp = Wv; dp = Wqkv + 20971520u; off = u - 2621440; }
  const float4* s4 = (const float4*)sp + off * 2;
  float4 a = s4[0], b = s4[1];
  bf16x8 o = { (bf16)a.x, (bf16)a.y, (bf16)a.z, (bf16)a.w,
               (bf16)b.x, (bf16)b.y, (bf16)b.z, (bf16)b.w };
  *(bf16x8*)(dp + off * 8) = o;
}

// ---------------- 256^2 single-barrier 8-phase GEMM (r10 schedule) -------
// SPLIT=0: by=swz/nbx, bx=swz%nbx; full K.
// SPLIT=1: kh=swz>>7, tile=swz&127, by=tile>>3, bx=tile&7; operands offset
//          by kh*2048 along K; C += kh*csplit. Inner loop identical.
template <typename OutT, int SPLIT>
__global__ __launch_bounds__(512, 2) void k_gemmCS(
    const bf16* __restrict__ A, const bf16* __restrict__ Bw,
    OutT* __restrict__ C, int lda, int Kloop, int ldc, int nbx, size_t csplit) {
  __shared__ __align__(16) bf16 lds[2][4][8192];  // 128 KiB
  const int tid = threadIdx.x;
  const int lane = tid & 63;
  const int w = tid >> 6;
  const int wm = w >> 2, wn = w & 3;  // 2M x 4N, wave out 128x64
  const int l16 = lane & 15, lh = lane >> 4;

  const int cpx = gridDim.x >> 3;
  const int swz = (blockIdx.x & 7) * cpx + (blockIdx.x >> 3);
  int by, bx;
  if (SPLIT) {
    const int kh = swz >> 7;
    const int t = swz & 127;
    by = t >> 3;
    bx = t & 7;
    A += (size_t)kh * 2048;
    Bw += (size_t)kh * 2048;
    C += (size_t)kh * csplit;
  } else {
    by = swz / nbx;
    bx = swz % nbx;
  }
  const size_t m0 = (size_t)by * 256, n0 = (size_t)bx * 256;

  const int row0 = tid >> 2;
  const int cOff = ((tid & 3) ^ ((row0 >> 1) & 3)) * 8;
  const bf16* pA0 = A + (m0 + row0) * lda + cOff;
  const bf16* pA1 = pA0 + (size_t)128 * lda;
  const bf16* pB0 = Bw + (n0 + row0) * lda + cOff;
  const bf16* pB1 = pB0 + (size_t)128 * lda;

#define SA(s, h, t)                                        \
  { const int kk = (t) * 64 + (h) * 32;                    \
    async16(pA0 + kk, &lds[s][h][0] + tid * 8);            \
    async16(pA1 + kk, &lds[s][h][0] + 4096 + tid * 8); }
#define SB(s, h, t)                                        \
  { const int kk = (t) * 64 + (h) * 32;                    \
    async16(pB0 + kk, &lds[s][2 + (h)][0] + tid * 8);      \
    async16(pB1 + kk, &lds[s][2 + (h)][0] + 4096 + tid * 8); }

#define RDA(s, u, mh)                                                 \
  UNROLL for (int x = 0; x < 4; ++x) {                                \
    int p = (wm * 128 + (mh) * 64 + x * 16 + l16) * 64 + lh * 16;     \
    p ^= ((p >> 7) & 3) << 4;                                         \
    Ar[x] = *(const bf16x8*)((const char*)&lds[s][u][0] + p);         \
  }
#define RDB(s, u)                                                     \
  UNROLL for (int y = 0; y < 4; ++y) {                                \
    int p = (wn * 64 + y * 16 + l16) * 64 + lh * 16;                  \
    p ^= ((p >> 7) & 3) << 4;                                         \
    Br[y] = *(const bf16x8*)((const char*)&lds[s][u][0] + p);         \
  }
#define MF(mh)                                                        \
  { __builtin_amdgcn_s_setprio(1);                                    \
    UNROLL for (int x = 0; x < 4; ++x)                                \
      UNROLL for (int y = 0; y < 4; ++y)                              \
        acc[(mh) * 4 + x][y] = __builtin_amdgcn_mfma_f32_16x16x32_bf16( \
            Ar[x], Br[y], acc[(mh) * 4 + x][y], 0, 0, 0);             \
    __builtin_amdgcn_s_setprio(0); }

  f32x4 acc[8][4] = {};
  const int NITER = Kloop >> 7;

  SA(0, 0, 0); SB(0, 0, 0); SA(0, 1, 0); SB(0, 1, 0); SA(1, 0, 1); SB(1, 0, 1);
  VMCNT(8);

#define ITER_BODY(i, LAST)                                                  \
  { const int t0 = 2 * (i), t1 = t0 + 1;                                    \
    bf16x8 Ar[4], Br[4];                                                    \
    BARR; RDA(0, 0, 0); RDB(0, 2); SA(1, 1, t1); MF(0);                     \
    BARR; RDA(0, 0, 1); SB(1, 1, t1); MF(1); VMCNT(8);                      \
    BARR; RDA(0, 1, 0); RDB(0, 3); if (!(LAST)) SA(0, 0, t0 + 2); MF(0);    \
    BARR; RDA(0, 1, 1); if (!(LAST)) SB(0, 0, t0 + 2); MF(1);               \
    if (LAST) { VMCNT(4); } else { VMCNT(8); }                              \
    BARR; RDA(1, 0, 0); RDB(1, 2); if (!(LAST)) SA(0, 1, t0 + 2); MF(0);    \
    BARR; RDA(1, 0, 1); if (!(LAST)) SB(0, 1, t0 + 2); MF(1);               \
    if (LAST) { VMCNT(0); } else { VMCNT(8); }                              \
    BARR; RDA(1, 1, 0); RDB(1, 3); if (!(LAST)) SA(1, 0, t1 + 2); MF(0);    \
    BARR; RDA(1, 1, 1); if (!(LAST)) SB(1, 0, t1 + 2); MF(1);               \
    if (!(LAST)) VMCNT(8); }

  for (int i = 0; i < NITER - 1; ++i) ITER_BODY(i, 0);
  ITER_BODY(NITER - 1, 1);

  UNROLL for (int mi = 0; mi < 8; ++mi) {
    size_t row = m0 + wm * 128 + mi * 16 + lh * 4;
    UNROLL for (int ni = 0; ni < 4; ++ni) {
      size_t col = n0 + wn * 64 + ni * 16 + l16;
      UNROLL for (int j = 0; j < 4; ++j)
        C[(row + j) * ldc + col] = (OutT)acc[mi][ni][j];
    }
  }
#undef SA
#undef SB
#undef RDA
#undef RDB
#undef MF
#undef ITER_BODY
}

// ---------------- split-K partial reduce: QKV cols 4096..6143 ------------
__global__ void k_redsum(const bf16* __restrict__ s, bf16* __restrict__ QKV) {
  int i = blockIdx.x * 256 + threadIdx.x;  // 1M threads x 8 elems
  int e = i * 8;
  int tok = e >> 11;
  int c = e & 2047;
  bf16x8 a = *(const bf16x8*)(s + e);
  bf16x8 b = *(const bf16x8*)(s + 8388608 + e);
  bf16x8 o;
  UNROLL for (int j = 0; j < 8; ++j) o[j] = (bf16)((float)a[j] + (float)b[j]);
  *(bf16x8*)(QKV + (size_t)tok * 6144 + 4096 + c) = o;
}

// ---------------- RoPE + scatter (Q,K), bf16x8-vectorized ----------------
__global__ void k_rope(const bf16* __restrict__ QKV, bf16* __restrict__ Qr,
                       bf16* __restrict__ Kr) {
  int gid = blockIdx.x * 256 + threadIdx.x;  // < 1310720
  int seg = gid & 7;
  int rest = gid >> 3;
  int slot = rest % 40;
  int tok = rest / 40;
  int s = tok & 2047;
  int b = tok >> 11;
  const bf16* src = QKV + (size_t)tok * 6144 + slot * 128 + seg * 8;
  bf16x8 a = *(const bf16x8*)src;
  bf16x8 c = *(const bf16x8*)(src + 64);
  bf16x8 o1v, o2v;
  const float scale = (slot < 32) ? 0.08838834764831845f : 1.0f;
  UNROLL for (int j = 0; j < 8; ++j) {
    int p = seg * 8 + j;
    float f = exp2f((float)p * (-13.287712379549449f / 64.0f));
    float sn, cn;
    sincosf((float)s * f, &sn, &cn);
    float x1 = (float)a[j], x2 = (float)c[j];
    o1v[j] = (bf16)((x1 * cn - x2 * sn) * scale);
    o2v[j] = (bf16)((x2 * cn + x1 * sn) * scale);
  }
  bf16* dst;
  if (slot < 32) {
    dst = Qr + (((size_t)b * 32 + slot) * 2048 + s) * 128 + seg * 8;
  } else {
    dst = Kr + (((size_t)b * 8 + (slot - 32)) * 2048 + s) * 128 + seg * 8;
  }
  *(bf16x8*)dst = o1v;
  *(bf16x8*)(dst + 64) = o2v;
}

// ---------------- V transpose: QKV[tok][5120+hkv*128+d] -> Vtg[b][hkv][d][s]
__global__ void k_vtrans(const bf16* __restrict__ QKV, bf16* __restrict__ Vtg) {
  __shared__ __align__(16) bf16 T[64 * 64];
  const int tid = threadIdx.x;
  const int dt = blockIdx.x & 1;
  const int st = (blockIdx.x >> 1) & 31;
  const int hh = blockIdx.x >> 6;
  const int hkv = hh & 7, b = hh >> 3;
  const int s0 = st * 64, d0 = dt * 64;
  const bf16* src = QKV + (size_t)(b * 2048 + s0) * 6144 + 5120 + hkv * 128 + d0;
  UNROLL for (int k = 0; k < 2; ++k) {
    int cc = tid * 2 + k;
    int r = cc >> 3, c8 = cc & 7;
    bf16x8 v = *(const bf16x8*)(src + (size_t)r * 6144 + c8 * 8);
    int byte = (r * 128 + c8 * 16) ^ ((r & 7) << 4);
    *(bf16x8*)((char*)T + byte) = v;
  }
  __syncthreads();
  bf16* dst = Vtg + ((size_t)(b * 8 + hkv) * 128 + d0) * 2048 + s0;
  UNROLL for (int k = 0; k < 2; ++k) {
    int cc = tid * 2 + k;
    int d = cc >> 3, s8 = cc & 7;
    bf16x8 v;
    UNROLL for (int j = 0; j < 8; ++j) {
      int s = s8 * 8 + j;
      int byte = (s * 128 + d * 2) ^ ((s & 7) << 4);
      v[j] = *(const bf16*)((const char*)T + byte);
    }
    *(bf16x8*)(dst + (size_t)d * 2048 + s8 * 8) = v;
  }
}

// ---------------- flash attention (causal, GQA 4:1) — r5 proven version --
__global__ __launch_bounds__(256, 2) void k_flash(
    const bf16* __restrict__ Qr, const bf16* __restrict__ Kr,
    const bf16* __restrict__ Vtg, bf16* __restrict__ Out) {
  __shared__ __align__(16) bf16 Kl[2][64 * 128];
  __shared__ __align__(16) bf16 Vl[2][128 * 64];
  __shared__ __align__(16) bf16 Pl[4][32 * 64];
  const int tid = threadIdx.x;
  const int lane = tid & 63;
  const int w = tid >> 6;
  const int l16 = lane & 15, lh = lane >> 4;
  const int pid = blockIdx.x & 7;
  const int hl = blockIdx.x >> 3;
  const int h = hl & 31, b = hl >> 5;
  const int hkv = h >> 2;
  const bf16* Kbase = Kr + ((size_t)(b * 8 + hkv)) * 2048 * 128;
  const bf16* Vbase = Vtg + ((size_t)(b * 8 + hkv)) * 128 * 2048;
  bf16* P = &Pl[w][0];

  int kOff[4], vOff[4], ldsOff[4];
  UNROLL for (int i = 0; i < 4; ++i) {
    int c = (w * 4 + i) * 64 + lane;
    ldsOff[i] = c * 8;
    int r = c >> 4, p = c & 15;
    kOff[i] = r * 128 + (p ^ (r & 7)) * 8;
    int r2 = c >> 3, p2 = c & 7;
    vOff[i] = r2 * 2048 + (p2 ^ (r2 & 7)) * 8;
  }

  for (int qi = 0; qi < 2; ++qi) {
    const int q = qi ? (15 - pid) : pid;
    const int q0 = q * 128;
    const int nt = 2 * q + 2;

    bf16x8 qf[2][4];
    UNROLL for (int m = 0; m < 2; ++m) {
      const bf16* qb = Qr + (((size_t)(b * 32 + h)) * 2048 + q0 + w * 32 + m * 16 + l16) * 128 + lh * 8;
      UNROLL for (int kc = 0; kc < 4; ++kc) qf[m][kc] = *(const bf16x8*)(qb + kc * 32);
    }
    f32x4 acc[2][8] = {};
    float mrow[2][4] = {{-1e30f, -1e30f, -1e30f, -1e30f}, {-1e30f, -1e30f, -1e30f, -1e30f}};
    float lrow[2][4] = {};

    UNROLL for (int i = 0; i < 4; ++i) {
      async16(Kbase + kOff[i], &Kl[0][0] + ldsOff[i]);
      async16(Vbase + vOff[i], &Vl[0][0] + ldsOff[i]);
    }
    __syncthreads();

    for (int t = 0; t < nt; ++t) {
      const int cur = t & 1;
      if (t + 1 < nt) {
        const int nb = t + 1;
        UNROLL for (int i = 0; i < 4; ++i) {
          async16(Kbase + (size_t)nb * 8192 + kOff[i], &Kl[cur ^ 1][0] + ldsOff[i]);
          async16(Vbase + (size_t)nb * 64 + vOff[i], &Vl[cur ^ 1][0] + ldsOff[i]);
        }
      }
      f32x4 sf[2][4] = {};
      UNROLL for (int ni = 0; ni < 4; ++ni) {
        int row = ni * 16 + l16;
        bf16x8 kf[4];
        UNROLL for (int kc = 0; kc < 4; ++kc) {
          int byte = (row * 256 + kc * 64 + lh * 16) ^ ((row & 7) << 4);
          kf[kc] = *(const bf16x8*)((const char*)&Kl[cur][0] + byte);
        }
        UNROLL for (int m = 0; m < 2; ++m)
          UNROLL for (int kc = 0; kc < 4; ++kc)
            sf[m][ni] = __builtin_amdgcn_mfma_f32_16x16x32_bf16(qf[m][kc], kf[kc], sf[m][ni], 0, 0, 0);
      }
      if (t >= 2 * q) {
        UNROLL for (int m = 0; m < 2; ++m)
          UNROLL for (int ni = 0; ni < 4; ++ni) {
            int key = t * 64 + ni * 16 + l16;
            UNROLL for (int j = 0; j < 4; ++j) {
              int rowg = q0 + w * 32 + m * 16 + lh * 4 + j;
              if (key > rowg) sf[m][ni][j] = -1e30f;
            }
          }
      }
      float corr[2][4];
      UNROLL for (int m = 0; m < 2; ++m)
        UNROLL for (int j = 0; j < 4; ++j) {
          float mx = fmaxf(fmaxf(sf[m][0][j], sf[m][1][j]), fmaxf(sf[m][2][j], sf[m][3][j]));
          mx = fmaxf(mx, __shfl_xor(mx, 1));
          mx = fmaxf(mx, __shfl_xor(mx, 2));
          mx = fmaxf(mx, __shfl_xor(mx, 4));
          mx = fmaxf(mx, __shfl_xor(mx, 8));
          float mn = fmaxf(mrow[m][j], mx);
          corr[m][j] = __expf(mrow[m][j] - mn);
          mrow[m][j] = mn;
          float rs = 0.f;
          UNROLL for (int ni = 0; ni < 4; ++ni) {
            float pv = __expf(sf[m][ni][j] - mn);
            sf[m][ni][j] = pv;
            rs += pv;
          }
          rs += __shfl_xor(rs, 1);
          rs += __shfl_xor(rs, 2);
          rs += __shfl_xor(rs, 4);
          rs += __shfl_xor(rs, 8);
          lrow[m][j] = lrow[m][j] * corr[m][j] + rs;
        }
      UNROLL for (int m = 0; m < 2; ++m)
        UNROLL for (int di = 0; di < 8; ++di)
          UNROLL for (int j = 0; j < 4; ++j) acc[m][di][j] *= corr[m][j];
      UNROLL for (int m = 0; m < 2; ++m)
        UNROLL for (int ni = 0; ni < 4; ++ni)
          UNROLL for (int j = 0; j < 4; ++j) {
            int row = m * 16 + lh * 4 + j;
            int byte = (row * 128 + ni * 32 + l16 * 2) ^ ((row & 7) << 4);
            *(bf16*)((char*)P + byte) = (bf16)sf[m][ni][j];
          }
      UNROLL for (int kc = 0; kc < 2; ++kc) {
        bf16x8 pa[2];
        UNROLL for (int m = 0; m < 2; ++m) {
          int row = m * 16 + l16;
          int byte = (row * 128 + kc * 64 + lh * 16) ^ ((row & 7) << 4);
          pa[m] = *(const bf16x8*)((const char*)P + byte);
        }
        UNROLL for (int di = 0; di < 8; ++di) {
          int d = di * 16 + l16;
          int byte = (d * 128 + kc * 64 + lh * 16) ^ ((d & 7) << 4);
          bf16x8 vb = *(const bf16x8*)((const char*)&Vl[cur][0] + byte);
          UNROLL for (int m = 0; m < 2; ++m)
            acc[m][di] = __builtin_amdgcn_mfma_f32_16x16x32_bf16(pa[m], vb, acc[m][di], 0, 0, 0);
        }
      }
      __syncthreads();
    }

    UNROLL for (int m = 0; m < 2; ++m)
      UNROLL for (int j = 0; j < 4; ++j) {
        float inv = 1.0f / lrow[m][j];
        int rowg = q0 + w * 32 + m * 16 + lh * 4 + j;
        bf16* ob = Out + ((size_t)(b * 2048) + rowg) * 4096 + h * 128 + l16;
        UNROLL for (int di = 0; di < 8; ++di)
          ob[di * 16] = (bf16)(acc[m][di][j] * inv);
      }
  }
}

// ---------------- launch ----------------
extern "C" void kernel_launch(void* const* d_in, const int* in_sizes, int n_in,
                              void* d_out, int out_size, void* d_ws, size_t ws_size,
                              hipStream_t stream) {
  const float* hidden = (const float*)d_in[0];
  const float* Wq = (const float*)d_in[3];
  const float* Wk = (const float*)d_in[4];
  const float* Wv = (const float*)d_in[5];
  const float* Wo = (const float*)d_in[6];
  float* out = (float*)d_out;

  // workspace layout (bytes):
  //   Xb   [4096*4096] bf16 @ 0        (reused as AttnOut)
  //   Wqkv [6144*4096] bf16 @ 32M      (reused as Wo_bf16 after gemm1)
  //   QKV  [4096*6144] bf16 @ 80M
  //   Qr   [2,32,2048,128] bf16 @ 128M (split-K partials live here first)
  //   Kr   [2,8,2048,128]  bf16 @ 160M
  //   Vtg  [2,8,128,2048]  bf16 @ 168M   total 176 MiB
  char* ws = (char*)d_ws;
  if (ws_size < 184549376u) return;
  bf16* Xb = (bf16*)(ws);
  bf16* Wqkv = (bf16*)(ws + 33554432u);
  bf16* QKV = (bf16*)(ws + 83886080u);
  bf16* Qr = (bf16*)(ws + 134217728u);
  bf16* Kr = (bf16*)(ws + 167772160u);
  bf16* Vtg = (bf16*)(ws + 176160768u);
  bf16* AttnO = Xb;
  bf16* Wob = Wqkv;
  bf16* Spart = Qr;  // 2 x 8388608 bf16 = 32 MB, dead before k_rope writes Qr

  k_cvt<<<8192, 256, 0, stream>>>(hidden, Xb, 2097152);
  k_cvtw3<<<12288, 256, 0, stream>>>(Wq, Wk, Wv, Wqkv);
  // gemm1A: Q-projection, 16x16 = 256 tiles, full K (one exact CU wave)
  k_gemmCS<bf16, 0><<<256, 512, 0, stream>>>(Xb, Wqkv, QKV, 4096, 4096, 6144, 16, 0);
  // gemm1B: K/V-projection, 128 tiles x 2 half-K = 256 blocks (one wave);
  // B operand pre-offset to rows 4096.. ; bf16 partials to Spart
  k_gemmCS<bf16, 1><<<256, 512, 0, stream>>>(
      Xb, Wqkv + (size_t)4096 * 4096, Spart, 4096, 2048, 2048, 8, 8388608u);
  k_redsum<<<4096, 256, 0, stream>>>(Spart, QKV);
  k_rope<<<5120, 256, 0, stream>>>(QKV, Qr, Kr);
  k_vtrans<<<1024, 256, 0, stream>>>(QKV, Vtg);
  k_cvt<<<8192, 256, 0, stream>>>(Wo, Wob, 2097152);
  k_flash<<<512, 256, 0, stream>>>(Qr, Kr, Vtg, AttnO);
  // O-proj: 16 x 16 = 256 blocks (one exact CU wave)
  k_gemmCS<float, 0><<<256, 512, 0, stream>>>(AttnO, Wob, out, 4096, 4096, 4096, 16, 0);
}

// Round 17
// 555.244 us; speedup vs baseline: 1.2047x; 1.0023x over previous
//
#include <hip/hip_runtime.h>
#include <hip/hip_bf16.h>

// Llama attention block: B=2, S=2048, H=4096, NH=32, NKV=8, HD=128, GQA 4:1.
// Pipeline (bf16 MFMA, fp32 accumulate):
//   1. convert hidden -> bf16; Wq/Wk/Wv -> bf16 in one dispatch
//   2. QKV = X @ Wqkv^T split for exact CU packing:
//      gemm1A: Q-projection cols 0..4095   = 256 tiles, full K  (1 wave)
//      gemm1B: K/V-proj   cols 4096..6143  = 128 tiles x 2 half-K (1 wave)
//      k_redsum: partial0+partial1 -> QKV cols 4096..6143
//   3. RoPE (Q,K) + scatter, bf16x8-vectorized; fold 1/sqrt(128) into Q
//   4. V transpose: QKV -> Vtg [b][hkv][128 d][2048 s]
//   5. flash attention (causal): KVBLK=64, dbuf LDS, XCD-coherent block
//      mapping (all 32 blocks of one (b,hkv) KV stream on one XCD -> KV
//      L2-resident, stage latency ~200cyc covered by 1-tile prefetch)
//   6. out = AttnOut @ Wo^T (fp32), same 256^2 8-phase GEMM

typedef __bf16 bf16;
typedef __bf16 bf16x8 __attribute__((ext_vector_type(8)));
typedef float f32x4 __attribute__((ext_vector_type(4)));

#define UNROLL _Pragma("unroll")

__device__ __forceinline__ void async16(const bf16* g, bf16* l) {
  __builtin_amdgcn_global_load_lds(
      (const __attribute__((address_space(1))) void*)g,
      (__attribute__((address_space(3))) void*)l,
      16, 0, 0);
}

#define BARR { __builtin_amdgcn_s_barrier(); }
#define VMCNT(n) { asm volatile("s_waitcnt vmcnt(" #n ")" ::: "memory"); }

// ---------------- fp32 -> bf16 convert (8 elem/thread) ----------------
__global__ void k_cvt(const float* __restrict__ s, bf16* __restrict__ d, int n8) {
  int i = blockIdx.x * 256 + threadIdx.x;
  if (i >= n8) return;
  const float4* sp = (const float4*)s + (size_t)i * 2;
  float4 a = sp[0], b = sp[1];
  bf16x8 o = { (bf16)a.x, (bf16)a.y, (bf16)a.z, (bf16)a.w,
               (bf16)b.x, (bf16)b.y, (bf16)b.z, (bf16)b.w };
  *(bf16x8*)(d + (size_t)i * 8) = o;
}

// ---------------- Wq/Wk/Wv converts in one dispatch ----------------------
__global__ void k_cvtw3(const float* __restrict__ Wq, const float* __restrict__ Wk,
                        const float* __restrict__ Wv, bf16* __restrict__ Wqkv) {
  int u = blockIdx.x * 256 + threadIdx.x;
  const float* sp;
  bf16* dp;
  size_t off;
  if (u < 2097152) { sp = Wq; dp = Wqkv; off = u; }
  else if (u < 2621440) { sp = Wk; dp = Wqkv + 16777216u; off = u - 2097152; }
  else { sp = Wv; dp = Wqkv + 20971520u; off = u - 2621440; }
  const float4* s4 = (const float4*)sp + off * 2;
  float4 a = s4[0], b = s4[1];
  bf16x8 o = { (bf16)a.x, (bf16)a.y, (bf16)a.z, (bf16)a.w,
               (bf16)b.x, (bf16)b.y, (bf16)b.z, (bf16)b.w };
  *(bf16x8*)(dp + off * 8) = o;
}

// ---------------- 256^2 single-barrier 8-phase GEMM (r10 schedule) -------
template <typename OutT, int SPLIT>
__global__ __launch_bounds__(512, 2) void k_gemmCS(
    const bf16* __restrict__ A, const bf16* __restrict__ Bw,
    OutT* __restrict__ C, int lda, int Kloop, int ldc, int nbx, size_t csplit) {
  __shared__ __align__(16) bf16 lds[2][4][8192];  // 128 KiB
  const int tid = threadIdx.x;
  const int lane = tid & 63;
  const int w = tid >> 6;
  const int wm = w >> 2, wn = w & 3;  // 2M x 4N, wave out 128x64
  const int l16 = lane & 15, lh = lane >> 4;

  const int cpx = gridDim.x >> 3;
  const int swz = (blockIdx.x & 7) * cpx + (blockIdx.x >> 3);
  int by, bx;
  if (SPLIT) {
    const int kh = swz >> 7;
    const int t = swz & 127;
    by = t >> 3;
    bx = t & 7;
    A += (size_t)kh * 2048;
    Bw += (size_t)kh * 2048;
    C += (size_t)kh * csplit;
  } else {
    by = swz / nbx;
    bx = swz % nbx;
  }
  const size_t m0 = (size_t)by * 256, n0 = (size_t)bx * 256;

  const int row0 = tid >> 2;
  const int cOff = ((tid & 3) ^ ((row0 >> 1) & 3)) * 8;
  const bf16* pA0 = A + (m0 + row0) * lda + cOff;
  const bf16* pA1 = pA0 + (size_t)128 * lda;
  const bf16* pB0 = Bw + (n0 + row0) * lda + cOff;
  const bf16* pB1 = pB0 + (size_t)128 * lda;

#define SA(s, h, t)                                        \
  { const int kk = (t) * 64 + (h) * 32;                    \
    async16(pA0 + kk, &lds[s][h][0] + tid * 8);            \
    async16(pA1 + kk, &lds[s][h][0] + 4096 + tid * 8); }
#define SB(s, h, t)                                        \
  { const int kk = (t) * 64 + (h) * 32;                    \
    async16(pB0 + kk, &lds[s][2 + (h)][0] + tid * 8);      \
    async16(pB1 + kk, &lds[s][2 + (h)][0] + 4096 + tid * 8); }

#define RDA(s, u, mh)                                                 \
  UNROLL for (int x = 0; x < 4; ++x) {                                \
    int p = (wm * 128 + (mh) * 64 + x * 16 + l16) * 64 + lh * 16;     \
    p ^= ((p >> 7) & 3) << 4;                                         \
    Ar[x] = *(const bf16x8*)((const char*)&lds[s][u][0] + p);         \
  }
#define RDB(s, u)                                                     \
  UNROLL for (int y = 0; y < 4; ++y) {                                \
    int p = (wn * 64 + y * 16 + l16) * 64 + lh * 16;                  \
    p ^= ((p >> 7) & 3) << 4;                                         \
    Br[y] = *(const bf16x8*)((const char*)&lds[s][u][0] + p);         \
  }
#define MF(mh)                                                        \
  { __builtin_amdgcn_s_setprio(1);                                    \
    UNROLL for (int x = 0; x < 4; ++x)                                \
      UNROLL for (int y = 0; y < 4; ++y)                              \
        acc[(mh) * 4 + x][y] = __builtin_amdgcn_mfma_f32_16x16x32_bf16( \
            Ar[x], Br[y], acc[(mh) * 4 + x][y], 0, 0, 0);             \
    __builtin_amdgcn_s_setprio(0); }

  f32x4 acc[8][4] = {};
  const int NITER = Kloop >> 7;

  SA(0, 0, 0); SB(0, 0, 0); SA(0, 1, 0); SB(0, 1, 0); SA(1, 0, 1); SB(1, 0, 1);
  VMCNT(8);

#define ITER_BODY(i, LAST)                                                  \
  { const int t0 = 2 * (i), t1 = t0 + 1;                                    \
    bf16x8 Ar[4], Br[4];                                                    \
    BARR; RDA(0, 0, 0); RDB(0, 2); SA(1, 1, t1); MF(0);                     \
    BARR; RDA(0, 0, 1); SB(1, 1, t1); MF(1); VMCNT(8);                      \
    BARR; RDA(0, 1, 0); RDB(0, 3); if (!(LAST)) SA(0, 0, t0 + 2); MF(0);    \
    BARR; RDA(0, 1, 1); if (!(LAST)) SB(0, 0, t0 + 2); MF(1);               \
    if (LAST) { VMCNT(4); } else { VMCNT(8); }                              \
    BARR; RDA(1, 0, 0); RDB(1, 2); if (!(LAST)) SA(0, 1, t0 + 2); MF(0);    \
    BARR; RDA(1, 0, 1); if (!(LAST)) SB(0, 1, t0 + 2); MF(1);               \
    if (LAST) { VMCNT(0); } else { VMCNT(8); }                              \
    BARR; RDA(1, 1, 0); RDB(1, 3); if (!(LAST)) SA(1, 0, t1 + 2); MF(0);    \
    BARR; RDA(1, 1, 1); if (!(LAST)) SB(1, 0, t1 + 2); MF(1);               \
    if (!(LAST)) VMCNT(8); }

  for (int i = 0; i < NITER - 1; ++i) ITER_BODY(i, 0);
  ITER_BODY(NITER - 1, 1);

  UNROLL for (int mi = 0; mi < 8; ++mi) {
    size_t row = m0 + wm * 128 + mi * 16 + lh * 4;
    UNROLL for (int ni = 0; ni < 4; ++ni) {
      size_t col = n0 + wn * 64 + ni * 16 + l16;
      UNROLL for (int j = 0; j < 4; ++j)
        C[(row + j) * ldc + col] = (OutT)acc[mi][ni][j];
    }
  }
#undef SA
#undef SB
#undef RDA
#undef RDB
#undef MF
#undef ITER_BODY
}

// ---------------- split-K partial reduce: QKV cols 4096..6143 ------------
__global__ void k_redsum(const bf16* __restrict__ s, bf16* __restrict__ QKV) {
  int i = blockIdx.x * 256 + threadIdx.x;
  int e = i * 8;
  int tok = e >> 11;
  int c = e & 2047;
  bf16x8 a = *(const bf16x8*)(s + e);
  bf16x8 b = *(const bf16x8*)(s + 8388608 + e);
  bf16x8 o;
  UNROLL for (int j = 0; j < 8; ++j) o[j] = (bf16)((float)a[j] + (float)b[j]);
  *(bf16x8*)(QKV + (size_t)tok * 6144 + 4096 + c) = o;
}

// ---------------- RoPE + scatter (Q,K), bf16x8-vectorized ----------------
__global__ void k_rope(const bf16* __restrict__ QKV, bf16* __restrict__ Qr,
                       bf16* __restrict__ Kr) {
  int gid = blockIdx.x * 256 + threadIdx.x;
  int seg = gid & 7;
  int rest = gid >> 3;
  int slot = rest % 40;
  int tok = rest / 40;
  int s = tok & 2047;
  int b = tok >> 11;
  const bf16* src = QKV + (size_t)tok * 6144 + slot * 128 + seg * 8;
  bf16x8 a = *(const bf16x8*)src;
  bf16x8 c = *(const bf16x8*)(src + 64);
  bf16x8 o1v, o2v;
  const float scale = (slot < 32) ? 0.08838834764831845f : 1.0f;
  UNROLL for (int j = 0; j < 8; ++j) {
    int p = seg * 8 + j;
    float f = exp2f((float)p * (-13.287712379549449f / 64.0f));
    float sn, cn;
    sincosf((float)s * f, &sn, &cn);
    float x1 = (float)a[j], x2 = (float)c[j];
    o1v[j] = (bf16)((x1 * cn - x2 * sn) * scale);
    o2v[j] = (bf16)((x2 * cn + x1 * sn) * scale);
  }
  bf16* dst;
  if (slot < 32) {
    dst = Qr + (((size_t)b * 32 + slot) * 2048 + s) * 128 + seg * 8;
  } else {
    dst = Kr + (((size_t)b * 8 + (slot - 32)) * 2048 + s) * 128 + seg * 8;
  }
  *(bf16x8*)dst = o1v;
  *(bf16x8*)(dst + 64) = o2v;
}

// ---------------- V transpose: QKV[tok][5120+hkv*128+d] -> Vtg[b][hkv][d][s]
__global__ void k_vtrans(const bf16* __restrict__ QKV, bf16* __restrict__ Vtg) {
  __shared__ __align__(16) bf16 T[64 * 64];
  const int tid = threadIdx.x;
  const int dt = blockIdx.x & 1;
  const int st = (blockIdx.x >> 1) & 31;
  const int hh = blockIdx.x >> 6;
  const int hkv = hh & 7, b = hh >> 3;
  const int s0 = st * 64, d0 = dt * 64;
  const bf16* src = QKV + (size_t)(b * 2048 + s0) * 6144 + 5120 + hkv * 128 + d0;
  UNROLL for (int k = 0; k < 2; ++k) {
    int cc = tid * 2 + k;
    int r = cc >> 3, c8 = cc & 7;
    bf16x8 v = *(const bf16x8*)(src + (size_t)r * 6144 + c8 * 8);
    int byte = (r * 128 + c8 * 16) ^ ((r & 7) << 4);
    *(bf16x8*)((char*)T + byte) = v;
  }
  __syncthreads();
  bf16* dst = Vtg + ((size_t)(b * 8 + hkv) * 128 + d0) * 2048 + s0;
  UNROLL for (int k = 0; k < 2; ++k) {
    int cc = tid * 2 + k;
    int d = cc >> 3, s8 = cc & 7;
    bf16x8 v;
    UNROLL for (int j = 0; j < 8; ++j) {
      int s = s8 * 8 + j;
      int byte = (s * 128 + d * 2) ^ ((s & 7) << 4);
      v[j] = *(const bf16*)((const char*)T + byte);
    }
    *(bf16x8*)(dst + (size_t)d * 2048 + s8 * 8) = v;
  }
}

// ---------------- flash attention (causal, GQA 4:1) ----------------------
// r5 body; block decode is XCD-coherent: stream = (b,hkv) determines
// blockIdx%8 so all 32 blocks sharing a KV stream land on one XCD
// (KV = 1 MB/stream, 2 streams/XCD -> L2-resident).
__global__ __launch_bounds__(256, 2) void k_flash(
    const bf16* __restrict__ Qr, const bf16* __restrict__ Kr,
    const bf16* __restrict__ Vtg, bf16* __restrict__ Out) {
  __shared__ __align__(16) bf16 Kl[2][64 * 128];
  __shared__ __align__(16) bf16 Vl[2][128 * 64];
  __shared__ __align__(16) bf16 Pl[4][32 * 64];
  const int tid = threadIdx.x;
  const int lane = tid & 63;
  const int w = tid >> 6;
  const int l16 = lane & 15, lh = lane >> 4;
  // XCD-coherent decode: stream = strhi*8 + (bid&7); inner = (bid>>3)&31
  const int bid = blockIdx.x;
  const int stream = ((bid >> 8) << 3) | (bid & 7);  // 0..15 = b*8+hkv
  const int inner = (bid >> 3) & 31;
  const int b = stream >> 3;
  const int hkv = stream & 7;
  const int h = hkv * 4 + (inner >> 3);
  const int pid = inner & 7;
  const bf16* Kbase = Kr + ((size_t)stream) * 2048 * 128;
  const bf16* Vbase = Vtg + ((size_t)stream) * 128 * 2048;
  bf16* P = &Pl[w][0];

  int kOff[4], vOff[4], ldsOff[4];
  UNROLL for (int i = 0; i < 4; ++i) {
    int c = (w * 4 + i) * 64 + lane;
    ldsOff[i] = c * 8;
    int r = c >> 4, p = c & 15;
    kOff[i] = r * 128 + (p ^ (r & 7)) * 8;
    int r2 = c >> 3, p2 = c & 7;
    vOff[i] = r2 * 2048 + (p2 ^ (r2 & 7)) * 8;
  }

  for (int qi = 0; qi < 2; ++qi) {
    const int q = qi ? (15 - pid) : pid;
    const int q0 = q * 128;
    const int nt = 2 * q + 2;

    bf16x8 qf[2][4];
    UNROLL for (int m = 0; m < 2; ++m) {
      const bf16* qb = Qr + (((size_t)(b * 32 + h)) * 2048 + q0 + w * 32 + m * 16 + l16) * 128 + lh * 8;
      UNROLL for (int kc = 0; kc < 4; ++kc) qf[m][kc] = *(const bf16x8*)(qb + kc * 32);
    }
    f32x4 acc[2][8] = {};
    float mrow[2][4] = {{-1e30f, -1e30f, -1e30f, -1e30f}, {-1e30f, -1e30f, -1e30f, -1e30f}};
    float lrow[2][4] = {};

    UNROLL for (int i = 0; i < 4; ++i) {
      async16(Kbase + kOff[i], &Kl[0][0] + ldsOff[i]);
      async16(Vbase + vOff[i], &Vl[0][0] + ldsOff[i]);
    }
    __syncthreads();

    for (int t = 0; t < nt; ++t) {
      const int cur = t & 1;
      if (t + 1 < nt) {
        const int nb = t + 1;
        UNROLL for (int i = 0; i < 4; ++i) {
          async16(Kbase + (size_t)nb * 8192 + kOff[i], &Kl[cur ^ 1][0] + ldsOff[i]);
          async16(Vbase + (size_t)nb * 64 + vOff[i], &Vl[cur ^ 1][0] + ldsOff[i]);
        }
      }
      f32x4 sf[2][4] = {};
      UNROLL for (int ni = 0; ni < 4; ++ni) {
        int row = ni * 16 + l16;
        bf16x8 kf[4];
        UNROLL for (int kc = 0; kc < 4; ++kc) {
          int byte = (row * 256 + kc * 64 + lh * 16) ^ ((row & 7) << 4);
          kf[kc] = *(const bf16x8*)((const char*)&Kl[cur][0] + byte);
        }
        UNROLL for (int m = 0; m < 2; ++m)
          UNROLL for (int kc = 0; kc < 4; ++kc)
            sf[m][ni] = __builtin_amdgcn_mfma_f32_16x16x32_bf16(qf[m][kc], kf[kc], sf[m][ni], 0, 0, 0);
      }
      if (t >= 2 * q) {
        UNROLL for (int m = 0; m < 2; ++m)
          UNROLL for (int ni = 0; ni < 4; ++ni) {
            int key = t * 64 + ni * 16 + l16;
            UNROLL for (int j = 0; j < 4; ++j) {
              int rowg = q0 + w * 32 + m * 16 + lh * 4 + j;
              if (key > rowg) sf[m][ni][j] = -1e30f;
            }
          }
      }
      float corr[2][4];
      UNROLL for (int m = 0; m < 2; ++m)
        UNROLL for (int j = 0; j < 4; ++j) {
          float mx = fmaxf(fmaxf(sf[m][0][j], sf[m][1][j]), fmaxf(sf[m][2][j], sf[m][3][j]));
          mx = fmaxf(mx, __shfl_xor(mx, 1));
          mx = fmaxf(mx, __shfl_xor(mx, 2));
          mx = fmaxf(mx, __shfl_xor(mx, 4));
          mx = fmaxf(mx, __shfl_xor(mx, 8));
          float mn = fmaxf(mrow[m][j], mx);
          corr[m][j] = __expf(mrow[m][j] - mn);
          mrow[m][j] = mn;
          float rs = 0.f;
          UNROLL for (int ni = 0; ni < 4; ++ni) {
            float pv = __expf(sf[m][ni][j] - mn);
            sf[m][ni][j] = pv;
            rs += pv;
          }
          rs += __shfl_xor(rs, 1);
          rs += __shfl_xor(rs, 2);
          rs += __shfl_xor(rs, 4);
          rs += __shfl_xor(rs, 8);
          lrow[m][j] = lrow[m][j] * corr[m][j] + rs;
        }
      UNROLL for (int m = 0; m < 2; ++m)
        UNROLL for (int di = 0; di < 8; ++di)
          UNROLL for (int j = 0; j < 4; ++j) acc[m][di][j] *= corr[m][j];
      UNROLL for (int m = 0; m < 2; ++m)
        UNROLL for (int ni = 0; ni < 4; ++ni)
          UNROLL for (int j = 0; j < 4; ++j) {
            int row = m * 16 + lh * 4 + j;
            int byte = (row * 128 + ni * 32 + l16 * 2) ^ ((row & 7) << 4);
            *(bf16*)((char*)P + byte) = (bf16)sf[m][ni][j];
          }
      UNROLL for (int kc = 0; kc < 2; ++kc) {
        bf16x8 pa[2];
        UNROLL for (int m = 0; m < 2; ++m) {
          int row = m * 16 + l16;
          int byte = (row * 128 + kc * 64 + lh * 16) ^ ((row & 7) << 4);
          pa[m] = *(const bf16x8*)((const char*)P + byte);
        }
        UNROLL for (int di = 0; di < 8; ++di) {
          int d = di * 16 + l16;
          int byte = (d * 128 + kc * 64 + lh * 16) ^ ((d & 7) << 4);
          bf16x8 vb = *(const bf16x8*)((const char*)&Vl[cur][0] + byte);
          UNROLL for (int m = 0; m < 2; ++m)
            acc[m][di] = __builtin_amdgcn_mfma_f32_16x16x32_bf16(pa[m], vb, acc[m][di], 0, 0, 0);
        }
      }
      __syncthreads();
    }

    UNROLL for (int m = 0; m < 2; ++m)
      UNROLL for (int j = 0; j < 4; ++j) {
        float inv = 1.0f / lrow[m][j];
        int rowg = q0 + w * 32 + m * 16 + lh * 4 + j;
        bf16* ob = Out + ((size_t)(b * 2048) + rowg) * 4096 + h * 128 + l16;
        UNROLL for (int di = 0; di < 8; ++di)
          ob[di * 16] = (bf16)(acc[m][di][j] * inv);
      }
  }
}

// ---------------- launch ----------------
extern "C" void kernel_launch(void* const* d_in, const int* in_sizes, int n_in,
                              void* d_out, int out_size, void* d_ws, size_t ws_size,
                              hipStream_t stream) {
  const float* hidden = (const float*)d_in[0];
  const float* Wq = (const float*)d_in[3];
  const float* Wk = (const float*)d_in[4];
  const float* Wv = (const float*)d_in[5];
  const float* Wo = (const float*)d_in[6];
  float* out = (float*)d_out;

  char* ws = (char*)d_ws;
  if (ws_size < 184549376u) return;
  bf16* Xb = (bf16*)(ws);
  bf16* Wqkv = (bf16*)(ws + 33554432u);
  bf16* QKV = (bf16*)(ws + 83886080u);
  bf16* Qr = (bf16*)(ws + 134217728u);
  bf16* Kr = (bf16*)(ws + 167772160u);
  bf16* Vtg = (bf16*)(ws + 176160768u);
  bf16* AttnO = Xb;
  bf16* Wob = Wqkv;
  bf16* Spart = Qr;  // 32 MB split-K partials; dead before k_rope writes Qr

  k_cvt<<<8192, 256, 0, stream>>>(hidden, Xb, 2097152);
  k_cvtw3<<<12288, 256, 0, stream>>>(Wq, Wk, Wv, Wqkv);
  // gemm1A: Q-projection, 256 tiles, full K (one exact CU wave)
  k_gemmCS<bf16, 0><<<256, 512, 0, stream>>>(Xb, Wqkv, QKV, 4096, 4096, 6144, 16, 0);
  // gemm1B: K/V-projection, 128 tiles x 2 half-K = 256 blocks (one wave)
  k_gemmCS<bf16, 1><<<256, 512, 0, stream>>>(
      Xb, Wqkv + (size_t)4096 * 4096, Spart, 4096, 2048, 2048, 8, 8388608u);
  k_redsum<<<4096, 256, 0, stream>>>(Spart, QKV);
  k_rope<<<5120, 256, 0, stream>>>(QKV, Qr, Kr);
  k_vtrans<<<1024, 256, 0, stream>>>(QKV, Vtg);
  k_cvt<<<8192, 256, 0, stream>>>(Wo, Wob, 2097152);
  k_flash<<<512, 256, 0, stream>>>(Qr, Kr, Vtg, AttnO);
  // O-proj: 256 blocks (one exact CU wave)
  k_gemmCS<float, 0><<<256, 512, 0, stream>>>(AttnO, Wob, out, 4096, 4096, 4096, 16, 0);
}